// Round 1
// baseline (3433.160 us; speedup 1.0000x reference)
//
#include <hip/hip_runtime.h>

// ---------- types ----------
typedef short v8s __attribute__((ext_vector_type(8)));
typedef float v4f __attribute__((ext_vector_type(4)));

static __device__ __forceinline__ unsigned short f2bf(float x) {
    unsigned u = __builtin_bit_cast(unsigned, x);
    unsigned r = (u + 0x7fffu + ((u >> 16) & 1u)) >> 16;
    return (unsigned short)r;
}

static __device__ __forceinline__ float sigm(float x) {
    return 1.f / (1.f + __expf(-x));
}
static __device__ __forceinline__ float tanh_fast(float x) {
    x = fminf(fmaxf(x, -15.f), 15.f);
    float e = __expf(2.f * x);
    return (e - 1.f) / (e + 1.f);
}

// ---------- elementwise f32 -> bf16 convert ----------
__global__ void cvt_bf16(const float* __restrict__ src, unsigned short* __restrict__ dst, int n) {
    int i = blockIdx.x * 256 + threadIdx.x;
    if (i < n) dst[i] = f2bf(src[i]);
}

// ---------- build X = concat(embed_table[slot_ids], value_embeds) as bf16 [16384][1024] ----------
__global__ void build_x(const int* __restrict__ slot_ids,
                        const float* __restrict__ value_embeds,
                        const float* __restrict__ embed_table,
                        unsigned short* __restrict__ X) {
    int r = blockIdx.x;           // r = b*64 + s
    int t = threadIdx.x;          // 256 threads
    int id = slot_ids[r];
    X[(long)r * 1024 + t] = f2bf(embed_table[id * 256 + t]);
#pragma unroll
    for (int i = 0; i < 3; i++) {
        int c = t + i * 256;
        X[(long)r * 1024 + 256 + c] = f2bf(value_embeds[(long)r * 768 + c]);
    }
}

// ---------- bf16 MFMA GEMM: C[M][N] = A[M][K] * Bt[N][K]^T ----------
// EPI=0: plain f32 store C[row*N+col]
// EPI=1: scatter into gi[2][64][256][1536]: row=(b*64+s), col=(d*1536+g)
template <int EPI>
__global__ __launch_bounds__(256) void gemm_bt(const unsigned short* __restrict__ A,
                                               const unsigned short* __restrict__ Bt,
                                               float* __restrict__ C,
                                               int M, int N, int K) {
    const int LDT = 72;  // padded LDS K-stride (shorts): breaks bank conflicts, keeps 16B align
    __shared__ unsigned short As[128 * 72];
    __shared__ unsigned short Bs[128 * 72];
    int tid = threadIdx.x;
    int lane = tid & 63;
    int wave = tid >> 6;
    int gm0 = blockIdx.y * 128;
    int gn0 = blockIdx.x * 128;
    int wm0 = (wave >> 1) * 64;
    int wn0 = (wave & 1) * 64;
    int q = lane >> 4;
    int l16 = lane & 15;

    v4f acc[4][4];
#pragma unroll
    for (int i = 0; i < 4; i++)
#pragma unroll
        for (int j = 0; j < 4; j++) acc[i][j] = v4f{0.f, 0.f, 0.f, 0.f};

    for (int k0 = 0; k0 < K; k0 += 64) {
#pragma unroll
        for (int l = tid; l < 1024; l += 256) {
            int row = l >> 3;
            int col = (l & 7) * 8;
            *(v8s*)&As[row * LDT + col] = *(const v8s*)&A[(long)(gm0 + row) * K + k0 + col];
            *(v8s*)&Bs[row * LDT + col] = *(const v8s*)&Bt[(long)(gn0 + row) * K + k0 + col];
        }
        __syncthreads();
#pragma unroll
        for (int kf = 0; kf < 2; kf++) {
            v8s af[4], bfr[4];
#pragma unroll
            for (int mi = 0; mi < 4; mi++)
                af[mi] = *(const v8s*)&As[(wm0 + mi * 16 + l16) * LDT + kf * 32 + q * 8];
#pragma unroll
            for (int ni = 0; ni < 4; ni++)
                bfr[ni] = *(const v8s*)&Bs[(wn0 + ni * 16 + l16) * LDT + kf * 32 + q * 8];
#pragma unroll
            for (int mi = 0; mi < 4; mi++)
#pragma unroll
                for (int ni = 0; ni < 4; ni++)
                    acc[mi][ni] = __builtin_amdgcn_mfma_f32_16x16x32_bf16(af[mi], bfr[ni], acc[mi][ni], 0, 0, 0);
        }
        __syncthreads();
    }

#pragma unroll
    for (int mi = 0; mi < 4; mi++)
#pragma unroll
        for (int ni = 0; ni < 4; ni++) {
            int col = gn0 + wn0 + ni * 16 + l16;
#pragma unroll
            for (int r = 0; r < 4; r++) {
                int row = gm0 + wm0 + mi * 16 + q * 4 + r;
                float v = acc[mi][ni][r];
                if (EPI == 0) {
                    C[(long)row * N + col] = v;
                } else {
                    int d = (col >= 1536) ? 1 : 0;
                    int g = col - d * 1536;
                    int b = row >> 6, s = row & 63;
                    C[(((long)(d * 64 + s)) * 256 + b) * 1536 + g] = v;
                }
            }
        }
}

// ---------- GRU recurrence ----------
// grid = 32 blocks: blockIdx.x = dir*16 + batch_block. Each block: 16 batch rows, all 64 steps.
// h state f32 in LDS; MFMA on bf16 copy; W_hh streamed from L2 (bf16 [2][1536][512]).
__global__ __launch_bounds__(256) void gru_rec(const float* __restrict__ gi,          // [2][64][256][1536]
                                               const unsigned short* __restrict__ Whh, // [2][1536][512]
                                               const float* __restrict__ bih_f,
                                               const float* __restrict__ bhh_f,
                                               const float* __restrict__ bih_b,
                                               const float* __restrict__ bhh_b,
                                               unsigned short* __restrict__ hout) {    // [256][64][1024]
    const int HB_LD = 520;  // padded bf16 row stride
    __shared__ float hf[16 * 512];
    __shared__ unsigned short hb[16 * HB_LD];
    int tid = threadIdx.x;
    int lane = tid & 63;
    int wave = tid >> 6;
    int q = lane >> 4, l16 = lane & 15;
    int d = blockIdx.x >> 4;
    int b0 = (blockIdx.x & 15) * 16;
    const float* bih = d ? bih_b : bih_f;
    const float* bhh = d ? bhh_b : bhh_f;
    const float* giD = gi + (long)d * 64 * 256 * 1536;
    const unsigned short* W = Whh + (long)d * 1536 * 512;

    for (int i = tid; i < 16 * 512; i += 256) hf[i] = 0.f;
    for (int i = tid; i < 16 * HB_LD; i += 256) hb[i] = 0;
    __syncthreads();

    for (int t = 0; t < 64; t++) {
        int s = d ? (63 - t) : t;
        // A fragments: h (bf16) [16 rows x 512]
        v8s af[16];
#pragma unroll
        for (int kf = 0; kf < 16; kf++)
            af[kf] = *(const v8s*)&hb[l16 * HB_LD + kf * 32 + q * 8];
        __syncthreads();  // all reads of hb done before rewrites

        // wave w owns h-columns j in [w*128, w*128+128)
#pragma unroll 1
        for (int jt = 0; jt < 8; jt++) {
            int n0 = wave * 128 + jt * 16;
            v4f aR = v4f{0.f, 0.f, 0.f, 0.f};
            v4f aZ = v4f{0.f, 0.f, 0.f, 0.f};
            v4f aN = v4f{0.f, 0.f, 0.f, 0.f};
#pragma unroll
            for (int kf = 0; kf < 16; kf++) {
                v8s b = *(const v8s*)&W[(long)(n0 + l16) * 512 + kf * 32 + q * 8];
                aR = __builtin_amdgcn_mfma_f32_16x16x32_bf16(af[kf], b, aR, 0, 0, 0);
            }
#pragma unroll
            for (int kf = 0; kf < 16; kf++) {
                v8s b = *(const v8s*)&W[(long)(512 + n0 + l16) * 512 + kf * 32 + q * 8];
                aZ = __builtin_amdgcn_mfma_f32_16x16x32_bf16(af[kf], b, aZ, 0, 0, 0);
            }
#pragma unroll
            for (int kf = 0; kf < 16; kf++) {
                v8s b = *(const v8s*)&W[(long)(1024 + n0 + l16) * 512 + kf * 32 + q * 8];
                aN = __builtin_amdgcn_mfma_f32_16x16x32_bf16(af[kf], b, aN, 0, 0, 0);
            }
            int j = n0 + l16;
#pragma unroll
            for (int r = 0; r < 4; r++) {
                int row = q * 4 + r;
                long gb = ((long)s * 256 + (b0 + row)) * 1536;
                float ir = giD[gb + j] + bih[j];
                float iz = giD[gb + 512 + j] + bih[512 + j];
                float in = giD[gb + 1024 + j] + bih[1024 + j];
                float grv = aR[r] + bhh[j];
                float gzv = aZ[r] + bhh[512 + j];
                float gnv = aN[r] + bhh[1024 + j];
                float rr = sigm(ir + grv);
                float zz = sigm(iz + gzv);
                float nn = tanh_fast(in + rr * gnv);
                float hp = hf[row * 512 + j];
                float hn = (1.f - zz) * nn + zz * hp;
                hf[row * 512 + j] = hn;
                unsigned short hbv = f2bf(hn);
                hb[row * HB_LD + j] = hbv;
                hout[(((long)(b0 + row)) * 64 + s) * 1024 + d * 512 + j] = hbv;
            }
        }
        __syncthreads();  // h updates visible before next step's fragment loads
    }
}

extern "C" void kernel_launch(void* const* d_in, const int* in_sizes, int n_in,
                              void* d_out, int out_size, void* d_ws, size_t ws_size,
                              hipStream_t stream) {
    const int* slot_ids = (const int*)d_in[0];
    const float* value_embeds = (const float*)d_in[1];
    const float* embed_table = (const float*)d_in[2];
    const float* W_ih_f = (const float*)d_in[3];
    const float* W_hh_f = (const float*)d_in[4];
    const float* b_ih_f = (const float*)d_in[5];
    const float* b_hh_f = (const float*)d_in[6];
    const float* W_ih_b = (const float*)d_in[7];
    const float* W_hh_b = (const float*)d_in[8];
    const float* b_ih_b = (const float*)d_in[9];
    const float* b_hh_b = (const float*)d_in[10];
    const float* W_proj = (const float*)d_in[11];
    float* out = (float*)d_out;
    char* ws = (char*)d_ws;

    // workspace layout (bytes)
    unsigned short* X = (unsigned short*)(ws + 0);              // 16384x1024 bf16 = 33,554,432
    float* gi = (float*)(ws + 33554432);                        // 2x64x256x1536 f32 = 201,326,592
    unsigned short* Wstk = (unsigned short*)(ws + 234881024);   // 3072x1024 bf16 = 6,291,456
    unsigned short* Whh = (unsigned short*)(ws + 241172480);    // 2x1536x512 bf16 = 3,145,728
    unsigned short* Wp = (unsigned short*)(ws + 244318208);     // 512x1024 bf16 = 1,048,576
    unsigned short* hout = X;  // alias: X is dead after gemm1

    cvt_bf16<<<6144, 256, 0, stream>>>(W_ih_f, Wstk, 1536 * 1024);
    cvt_bf16<<<6144, 256, 0, stream>>>(W_ih_b, Wstk + 1536 * 1024, 1536 * 1024);
    cvt_bf16<<<3072, 256, 0, stream>>>(W_hh_f, Whh, 1536 * 512);
    cvt_bf16<<<3072, 256, 0, stream>>>(W_hh_b, Whh + 1536 * 512, 1536 * 512);
    cvt_bf16<<<2048, 256, 0, stream>>>(W_proj, Wp, 512 * 1024);
    build_x<<<16384, 256, 0, stream>>>(slot_ids, value_embeds, embed_table, X);

    // gi = X @ [Wih_f; Wih_b]^T   (M=16384, N=3072, K=1024)
    gemm_bt<1><<<dim3(24, 128), 256, 0, stream>>>(X, Wstk, gi, 16384, 3072, 1024);

    // recurrence (both directions)
    gru_rec<<<32, 256, 0, stream>>>(gi, Whh, b_ih_f, b_hh_f, b_ih_b, b_hh_b, hout);

    // out = hcat @ W_proj^T   (M=16384, N=512, K=1024)
    gemm_bt<0><<<dim3(4, 128), 256, 0, stream>>>(hout, Wp, out, 16384, 512, 1024);
}

// Round 2
// 3321.717 us; speedup vs baseline: 1.0335x; 1.0335x over previous
//
#include <hip/hip_runtime.h>

// ---------- types ----------
typedef short v8s __attribute__((ext_vector_type(8)));
typedef float v4f __attribute__((ext_vector_type(4)));

static __device__ __forceinline__ unsigned short f2bf(float x) {
    unsigned u = __builtin_bit_cast(unsigned, x);
    unsigned r = (u + 0x7fffu + ((u >> 16) & 1u)) >> 16;
    return (unsigned short)r;
}

static __device__ __forceinline__ float sigm(float x) {
    return 1.f / (1.f + __expf(-x));
}
static __device__ __forceinline__ float tanh_fast(float x) {
    x = fminf(fmaxf(x, -15.f), 15.f);
    float e = __expf(2.f * x);
    return (e - 1.f) / (e + 1.f);
}

// ---------- elementwise f32 -> bf16 convert ----------
__global__ void cvt_bf16(const float* __restrict__ src, unsigned short* __restrict__ dst, int n) {
    int i = blockIdx.x * 256 + threadIdx.x;
    if (i < n) dst[i] = f2bf(src[i]);
}

// ---------- repack W_hh (f32 [1536][512]) into MFMA B-fragment order ----------
// dst: [96 tiles][16 kf][64 lane][8 i] bf16, per dir.
// B element (n, k): n = tile*16 + (lane&15), k = kf*32 + (lane>>4)*8 + i.
__global__ void repack_whh(const float* __restrict__ src, unsigned short* __restrict__ dst) {
    long e = (long)blockIdx.x * 256 + threadIdx.x;  // < 786432
    int i = e & 7;
    int lane = (e >> 3) & 63;
    int kf = (e >> 9) & 15;
    int T = (int)(e >> 13);  // 0..95
    int gcol = T * 16 + (lane & 15);
    int k = kf * 32 + (lane >> 4) * 8 + i;
    dst[e] = f2bf(src[(long)gcol * 512 + k]);
}

// ---------- build X = concat(embed_table[slot_ids], value_embeds) as bf16 [16384][1024] ----------
__global__ void build_x(const int* __restrict__ slot_ids,
                        const float* __restrict__ value_embeds,
                        const float* __restrict__ embed_table,
                        unsigned short* __restrict__ X) {
    int r = blockIdx.x;           // r = b*64 + s
    int t = threadIdx.x;          // 256 threads
    int id = slot_ids[r];
    X[(long)r * 1024 + t] = f2bf(embed_table[id * 256 + t]);
#pragma unroll
    for (int i = 0; i < 3; i++) {
        int c = t + i * 256;
        X[(long)r * 1024 + 256 + c] = f2bf(value_embeds[(long)r * 768 + c]);
    }
}

// ---------- bf16 MFMA GEMM: C[M][N] = A[M][K] * Bt[N][K]^T ----------
template <int EPI>
__global__ __launch_bounds__(256) void gemm_bt(const unsigned short* __restrict__ A,
                                               const unsigned short* __restrict__ Bt,
                                               float* __restrict__ C,
                                               int M, int N, int K) {
    const int LDT = 72;
    __shared__ unsigned short As[128 * 72];
    __shared__ unsigned short Bs[128 * 72];
    int tid = threadIdx.x;
    int lane = tid & 63;
    int wave = tid >> 6;
    int gm0 = blockIdx.y * 128;
    int gn0 = blockIdx.x * 128;
    int wm0 = (wave >> 1) * 64;
    int wn0 = (wave & 1) * 64;
    int q = lane >> 4;
    int l16 = lane & 15;

    v4f acc[4][4];
#pragma unroll
    for (int i = 0; i < 4; i++)
#pragma unroll
        for (int j = 0; j < 4; j++) acc[i][j] = v4f{0.f, 0.f, 0.f, 0.f};

    for (int k0 = 0; k0 < K; k0 += 64) {
#pragma unroll
        for (int l = tid; l < 1024; l += 256) {
            int row = l >> 3;
            int col = (l & 7) * 8;
            *(v8s*)&As[row * LDT + col] = *(const v8s*)&A[(long)(gm0 + row) * K + k0 + col];
            *(v8s*)&Bs[row * LDT + col] = *(const v8s*)&Bt[(long)(gn0 + row) * K + k0 + col];
        }
        __syncthreads();
#pragma unroll
        for (int kf = 0; kf < 2; kf++) {
            v8s af[4], bfr[4];
#pragma unroll
            for (int mi = 0; mi < 4; mi++)
                af[mi] = *(const v8s*)&As[(wm0 + mi * 16 + l16) * LDT + kf * 32 + q * 8];
#pragma unroll
            for (int ni = 0; ni < 4; ni++)
                bfr[ni] = *(const v8s*)&Bs[(wn0 + ni * 16 + l16) * LDT + kf * 32 + q * 8];
#pragma unroll
            for (int mi = 0; mi < 4; mi++)
#pragma unroll
                for (int ni = 0; ni < 4; ni++)
                    acc[mi][ni] = __builtin_amdgcn_mfma_f32_16x16x32_bf16(af[mi], bfr[ni], acc[mi][ni], 0, 0, 0);
        }
        __syncthreads();
    }

#pragma unroll
    for (int mi = 0; mi < 4; mi++)
#pragma unroll
        for (int ni = 0; ni < 4; ni++) {
            int col = gn0 + wn0 + ni * 16 + l16;
#pragma unroll
            for (int r = 0; r < 4; r++) {
                int row = gm0 + wm0 + mi * 16 + q * 4 + r;
                float v = acc[mi][ni][r];
                if (EPI == 0) {
                    C[(long)row * N + col] = v;
                } else {
                    int d = (col >= 1536) ? 1 : 0;
                    int g = col - d * 1536;
                    int b = row >> 6, s = row & 63;
                    C[(((long)(d * 64 + s)) * 256 + b) * 1536 + g] = v;
                }
            }
        }
}

// ---------- GRU recurrence ----------
// 32 blocks x 1024 threads. blockIdx.x = dir*16 + batch_block (16 rows each).
// 16 waves; wave w owns h-columns [w*32, w*32+32). h f32 state in registers
// (lane-private), bf16 h double-buffered in LDS for MFMA A-operand.
// W_hh pre-repacked into fragment order -> every B load is one coalesced 4KB wave load.
__global__ __launch_bounds__(1024) void gru_rec(const float* __restrict__ gi,           // [2][64][256][1536]
                                                const unsigned short* __restrict__ Wpk, // [2][96][16][64][8]
                                                const float* __restrict__ bih_f,
                                                const float* __restrict__ bhh_f,
                                                const float* __restrict__ bih_b,
                                                const float* __restrict__ bhh_b,
                                                unsigned short* __restrict__ hout) {    // [256][64][1024]
    const int HB_LD = 520;
    __shared__ unsigned short hb2[2][16 * HB_LD];
    int tid = threadIdx.x;
    int lane = tid & 63;
    int wave = tid >> 6;          // 0..15
    int q = lane >> 4, l16 = lane & 15;
    int d = blockIdx.x >> 4;
    int b0 = (blockIdx.x & 15) * 16;
    const float* bih = d ? bih_b : bih_f;
    const float* bhh = d ? bhh_b : bhh_f;
    const float* giD = gi + (long)d * 64 * 256 * 1536;
    const unsigned short* W = Wpk + (long)d * 96 * 8192;

    // per-lane biases for owned columns
    float bi[2][3], bh[2][3];
#pragma unroll
    for (int c = 0; c < 2; c++) {
        int j = wave * 32 + c * 16 + l16;
        bi[c][0] = bih[j]; bi[c][1] = bih[512 + j]; bi[c][2] = bih[1024 + j];
        bh[c][0] = bhh[j]; bh[c][1] = bhh[512 + j]; bh[c][2] = bhh[1024 + j];
    }

    // W fragment base pointers (constant over time)
    const unsigned short* wp[2][3];
#pragma unroll
    for (int c = 0; c < 2; c++)
#pragma unroll
        for (int g = 0; g < 3; g++) {
            int tile = g * 32 + wave * 2 + c;
            wp[c][g] = W + (long)tile * 8192 + lane * 8;
        }

    float hreg[2][4];
#pragma unroll
    for (int c = 0; c < 2; c++)
#pragma unroll
        for (int r = 0; r < 4; r++) hreg[c][r] = 0.f;

    for (int i = tid; i < 16 * HB_LD; i += 1024) hb2[0][i] = 0;
    __syncthreads();

    for (int t = 0; t < 64; t++) {
        int s = d ? (63 - t) : t;
        const unsigned short* cur = hb2[t & 1];
        unsigned short* nxt = hb2[(t + 1) & 1];

        v4f acc[2][3];
#pragma unroll
        for (int c = 0; c < 2; c++)
#pragma unroll
            for (int g = 0; g < 3; g++) acc[c][g] = v4f{0.f, 0.f, 0.f, 0.f};

#pragma unroll
        for (int hh = 0; hh < 2; hh++) {
            v8s af[8];
#pragma unroll
            for (int k8 = 0; k8 < 8; k8++)
                af[k8] = *(const v8s*)&cur[l16 * HB_LD + (hh * 8 + k8) * 32 + q * 8];
#pragma unroll
            for (int c = 0; c < 2; c++)
#pragma unroll
                for (int g = 0; g < 3; g++) {
                    const unsigned short* p = wp[c][g] + (long)hh * 8 * 512;
#pragma unroll
                    for (int k8 = 0; k8 < 8; k8++) {
                        v8s b = *(const v8s*)&p[(long)k8 * 512];
                        acc[c][g] = __builtin_amdgcn_mfma_f32_16x16x32_bf16(af[k8], b, acc[c][g], 0, 0, 0);
                    }
                }
        }

#pragma unroll
        for (int c = 0; c < 2; c++) {
            int j = wave * 32 + c * 16 + l16;
#pragma unroll
            for (int r = 0; r < 4; r++) {
                int row = q * 4 + r;
                long gb = ((long)s * 256 + (b0 + row)) * 1536;
                float ir = giD[gb + j] + bi[c][0];
                float iz = giD[gb + 512 + j] + bi[c][1];
                float in = giD[gb + 1024 + j] + bi[c][2];
                float rr = sigm(ir + acc[c][0][r] + bh[c][0]);
                float zz = sigm(iz + acc[c][1][r] + bh[c][1]);
                float nn = tanh_fast(in + rr * (acc[c][2][r] + bh[c][2]));
                float hn = (1.f - zz) * nn + zz * hreg[c][r];
                hreg[c][r] = hn;
                unsigned short hv = f2bf(hn);
                nxt[row * HB_LD + j] = hv;
                hout[(((long)(b0 + row)) * 64 + s) * 1024 + d * 512 + j] = hv;
            }
        }
        __syncthreads();
    }
}

extern "C" void kernel_launch(void* const* d_in, const int* in_sizes, int n_in,
                              void* d_out, int out_size, void* d_ws, size_t ws_size,
                              hipStream_t stream) {
    const int* slot_ids = (const int*)d_in[0];
    const float* value_embeds = (const float*)d_in[1];
    const float* embed_table = (const float*)d_in[2];
    const float* W_ih_f = (const float*)d_in[3];
    const float* W_hh_f = (const float*)d_in[4];
    const float* b_ih_f = (const float*)d_in[5];
    const float* b_hh_f = (const float*)d_in[6];
    const float* W_ih_b = (const float*)d_in[7];
    const float* W_hh_b = (const float*)d_in[8];
    const float* b_ih_b = (const float*)d_in[9];
    const float* b_hh_b = (const float*)d_in[10];
    const float* W_proj = (const float*)d_in[11];
    float* out = (float*)d_out;
    char* ws = (char*)d_ws;

    // workspace layout (bytes)
    unsigned short* X = (unsigned short*)(ws + 0);              // 16384x1024 bf16 = 33,554,432
    float* gi = (float*)(ws + 33554432);                        // 2x64x256x1536 f32 = 201,326,592
    unsigned short* Wstk = (unsigned short*)(ws + 234881024);   // 3072x1024 bf16 = 6,291,456
    unsigned short* Wpk = (unsigned short*)(ws + 241172480);    // 2x96x16x64x8 bf16 = 3,145,728
    unsigned short* Wp = (unsigned short*)(ws + 244318208);     // 512x1024 bf16 = 1,048,576
    unsigned short* hout = X;  // alias: X is dead after gemm1

    cvt_bf16<<<6144, 256, 0, stream>>>(W_ih_f, Wstk, 1536 * 1024);
    cvt_bf16<<<6144, 256, 0, stream>>>(W_ih_b, Wstk + 1536 * 1024, 1536 * 1024);
    repack_whh<<<3072, 256, 0, stream>>>(W_hh_f, Wpk);
    repack_whh<<<3072, 256, 0, stream>>>(W_hh_b, Wpk + 786432);
    cvt_bf16<<<2048, 256, 0, stream>>>(W_proj, Wp, 512 * 1024);
    build_x<<<16384, 256, 0, stream>>>(slot_ids, value_embeds, embed_table, X);

    // gi = X @ [Wih_f; Wih_b]^T   (M=16384, N=3072, K=1024)
    gemm_bt<1><<<dim3(24, 128), 256, 0, stream>>>(X, Wstk, gi, 16384, 3072, 1024);

    // recurrence (both directions)
    gru_rec<<<32, 1024, 0, stream>>>(gi, Wpk, b_ih_f, b_hh_f, b_ih_b, b_hh_b, hout);

    // out = hcat @ W_proj^T   (M=16384, N=512, K=1024)
    gemm_bt<0><<<dim3(4, 128), 256, 0, stream>>>(hout, Wp, out, 16384, 512, 1024);
}